// Round 11
// baseline (207.155 us; speedup 1.0000x reference)
//
#include <hip/hip_runtime.h>
#include <stdint.h>

#define NB 16
#define NN 4096
#define KK 10
#define NL 11       // pass1 list size: 11th-smallest oct-min -> tau
#define FD 64
#define TOTAL (NB * NN)
#define NW 8        // waves per knn block
#define CH 512      // candidates per wave chunk (NW*CH == NN)
#define SOCT 16     // sampled octs per chunk (first 128 cands) for pass1
#define QG 64       // queries per block (one per lane)
#define WCAP 32     // survivor cap per (query,wave) cell (mean ~6, P(ovfl)~0)
#define WPITCH 33   // cell pitch in halfwords

#define INFF __int_as_float(0x7f800000)

typedef float f2 __attribute__((ext_vector_type(2)));

// Packed membership distance: candidate coords are wave-uniform f2 (SGPR
// pairs); vx2/vy2/vz2/sqi are per-lane splats. Lowers to v_pk_fma_f32 with
// one SGPR-pair operand. MEMBERSHIP ONLY - final keys use d2exact.
__device__ __forceinline__ f2 FdP(f2 cx, f2 cy, f2 cz, f2 cq,
                                  f2 vx2, f2 vy2, f2 vz2, f2 sqi2) {
#pragma clang fp contract(fast)
    f2 t = sqi2 + cq;
    t = vx2 * cx + t;
    t = vy2 * cy + t;
    t = vz2 * cz + t;
    return t;
}

// EXACT numpy rounding - frozen since round 1 (absmax 0.75). DO NOT CHANGE.
__device__ __forceinline__ uint32_t d2exact(float mx, float my, float mz, float sqi,
                                            float cx, float cy, float cz, float cw) {
    float dot = __fadd_rn(__fadd_rn(__fmul_rn(mx, cx), __fmul_rn(my, cy)),
                          __fmul_rn(mz, cz));
    float d2 = __fsub_rn(__fadd_rn(sqi, cw), __fmul_rn(2.0f, dot));
    return __float_as_uint(d2);
}

// ---------------------------------------------------------------------------
// Prep: pair-packed positions + zero cnt.
// pp4[2p]={x0,x1,y0,y1}, pp4[2p+1]={z0,z1,q0,q1}, q=(x*x+y*y)+z*z numpy-exact.
// ---------------------------------------------------------------------------
__global__ __launch_bounds__(256) void prep_kernel(const float* __restrict__ pos,
                                                   float4* __restrict__ pp4,
                                                   int* __restrict__ cnt) {
    const int p = blockIdx.x * 256 + threadIdx.x;  // pair index, < TOTAL/2
    const float* s = pos + (size_t)p * 6;
    float x0 = s[0], y0 = s[1], z0 = s[2];
    float x1 = s[3], y1 = s[4], z1 = s[5];
    float q0 = __fadd_rn(__fadd_rn(__fmul_rn(x0, x0), __fmul_rn(y0, y0)),
                         __fmul_rn(z0, z0));
    float q1 = __fadd_rn(__fadd_rn(__fmul_rn(x1, x1), __fmul_rn(y1, y1)),
                         __fmul_rn(z1, z1));
    pp4[2 * p + 0] = make_float4(x0, x1, y0, y1);
    pp4[2 * p + 1] = make_float4(z0, z1, q0, q1);
    cnt[2 * p + 0] = 0;
    cnt[2 * p + 1] = 0;
}

// ---------------------------------------------------------------------------
// kNN: block = 512 thr = 8 waves; lane = query, wave = 512-cand chunk.
// Candidate data wave-uniform (scalar loads as f2); distance = v_pk_fma (2
// slots/cand). Pass1: top-11 oct-mins over first 128 cands (halved sample;
// tau = 11th-smallest octmin of the 1024-cand union is still >= true 10th
// non-self by the order-stat bound - exact rescore absorbs the extra
// survivors). Pass2: packed full-chunk replay with pair-granularity push
// guards into private (query,wave) u16 LDS cells. Select: exact-rescore
// survivors, (d2,idx) top-10, skip self, write edges.
// Batch = blockIdx&15 -> XCD L2 affinity for the 1MB/batch pp4 slice.
// ---------------------------------------------------------------------------
__global__ __launch_bounds__(512, 8) void knn_kernel(const float4* __restrict__ pp4,
                                                     int* __restrict__ cnt,
                                                     int* __restrict__ colfix,
                                                     int* __restrict__ nbr) {
    __shared__ uint32_t smem[8448];      // pass1 lists (5632 w) then u16 pools (8448 w)
    __shared__ float tau_s[QG];
    __shared__ uint32_t qcntw[QG * NW];
    float* listf = (float*)smem;
    uint16_t* pool16 = (uint16_t*)smem;

    const int tid = threadIdx.x;
    const int lane = tid & 63;
    const int w = __builtin_amdgcn_readfirstlane(tid >> 6);
    const int batch = blockIdx.x & 15;                  // XCD-affinity swizzle
    const int qloc = ((blockIdx.x >> 4) << 6) | lane;   // batch-local query idx
    const int gbase = batch << 12;
    const int gq = gbase + qloc;

    // my query position (from pair-packed array)
    float4 mA = pp4[(gq >> 1) * 2 + 0];
    float4 mB = pp4[(gq >> 1) * 2 + 1];
    const bool hi = (qloc & 1);
    const float mx = hi ? mA.y : mA.x;
    const float my = hi ? mA.w : mA.z;
    const float mz = hi ? mB.y : mB.x;
    const float sqi = hi ? mB.w : mB.z;
    const f2 vx22 = {__fmul_rn(-2.0f, mx), __fmul_rn(-2.0f, mx)};
    const f2 vy22 = {__fmul_rn(-2.0f, my), __fmul_rn(-2.0f, my)};
    const f2 vz22 = {__fmul_rn(-2.0f, mz), __fmul_rn(-2.0f, mz)};
    const f2 sqi22 = {sqi, sqi};

    // chunk base as f2: pair p -> f2s {x01,y01,z01,q01} at 4p..4p+3
    const f2* __restrict__ cp2 = (const f2*)(pp4 + (size_t)(gbase + w * CH));

#define D8P(cb2)                                                      \
    f2 X0 = (cb2)[0],  Y0 = (cb2)[1],  Z0 = (cb2)[2],  Q0 = (cb2)[3]; \
    f2 X1 = (cb2)[4],  Y1 = (cb2)[5],  Z1 = (cb2)[6],  Q1 = (cb2)[7]; \
    f2 X2 = (cb2)[8],  Y2 = (cb2)[9],  Z2 = (cb2)[10], Q2 = (cb2)[11];\
    f2 X3 = (cb2)[12], Y3 = (cb2)[13], Z3 = (cb2)[14], Q3 = (cb2)[15];\
    f2 e0 = FdP(X0, Y0, Z0, Q0, vx22, vy22, vz22, sqi22);             \
    f2 e1 = FdP(X1, Y1, Z1, Q1, vx22, vy22, vz22, sqi22);             \
    f2 e2 = FdP(X2, Y2, Z2, Q2, vx22, vy22, vz22, sqi22);             \
    f2 e3 = FdP(X3, Y3, Z3, Q3, vx22, vy22, vz22, sqi22);

    // ---- pass 1: top-11 oct-mins over sampled first 128 cands of chunk
    float L[NL];
#pragma unroll
    for (int t = 0; t < NL; t++) L[t] = INFF;

#pragma unroll 2
    for (int o = 0; o < SOCT; ++o) {
        const f2* cb2 = cp2 + o * 16;
        D8P(cb2);
        float m = fminf(fminf(fminf(e0.x, e0.y), fminf(e1.x, e1.y)),
                        fminf(fminf(e2.x, e2.y), fminf(e3.x, e3.y)));
#pragma unroll
        for (int t = 0; t < NL - 1; ++t) L[t] = __builtin_amdgcn_fmed3f(L[t], L[t + 1], m);
        L[NL - 1] = fminf(L[NL - 1], m);
    }
#pragma unroll
    for (int t = 0; t < NL; t++) listf[tid * NL + t] = L[t];
    __syncthreads();

    // ---- merge: 11th-smallest oct-min of the 8-list union -> tau
    if (tid < QG) {
        int p[NW];
#pragma unroll
        for (int u = 0; u < NW; u++) p[u] = NL - 1;  // descending lists; tail = min
        float tau = INFF;
        for (int it = 0; it < NL; ++it) {
            float best = INFF;
            int bw = 0;
#pragma unroll
            for (int u = 0; u < NW; u++) {
                float v = (p[u] >= 0) ? listf[((u << 6) | tid) * NL + p[u]] : INFF;
                if (v < best) { best = v; bw = u; }
            }
            p[bw]--;
            tau = best;
        }
        tau_s[tid] = tau;
    }
    __syncthreads();  // merge reads done; pool16 may now overwrite list region

    // ---- pass 2: packed full-chunk replay into private (query,wave) u16 cell
    // guard: covers |packed - exact| rigorously (order-stat bound + eps)
    const float tau = tau_s[lane] * 1.0001f + 1e-5f;
    const uint32_t cell0 = (uint32_t)((lane * NW + w) * WPITCH);  // halfword idx
    uint32_t cpos = cell0;
#pragma unroll 4
    for (int o = 0; o < CH / 8; ++o) {
        const f2* cb2 = cp2 + o * 16;
        D8P(cb2);
        const uint32_t jb = (uint32_t)(w * CH + o * 8);
        bool h0 = e0.x <= tau, h1 = e0.y <= tau, h2 = e1.x <= tau, h3 = e1.y <= tau;
        bool h4 = e2.x <= tau, h5 = e2.y <= tau, h6 = e3.x <= tau, h7 = e3.y <= tau;
#define PUSH(hv, off)                                              \
        if ((hv) && cpos < cell0 + WCAP) {                         \
            pool16[cpos] = (uint16_t)(jb + (off));                 \
            cpos++;                                                \
        }
        if (h0 | h1) { PUSH(h0, 0) PUSH(h1, 1) }
        if (h2 | h3) { PUSH(h2, 2) PUSH(h3, 3) }
        if (h4 | h5) { PUSH(h4, 4) PUSH(h5, 5) }
        if (h6 | h7) { PUSH(h6, 6) PUSH(h7, 7) }
#undef PUSH
    }
    qcntw[lane * NW + w] = cpos - cell0;
    __syncthreads();

    // ---- select: exact rescore of survivors, (d2,idx) top-10, skip self
    if (tid < QG) {
        uint64_t S[KK];
#pragma unroll
        for (int t = 0; t < KK; t++) S[t] = ~0ull;
#pragma unroll
        for (int u = 0; u < NW; u++) {
            uint32_t c2 = qcntw[tid * NW + u];
            const uint16_t* st = pool16 + (tid * NW + u) * WPITCH;
            for (uint32_t e = 0; e < c2; ++e) {
                uint32_t ix = st[e];
                if (ix == (uint32_t)qloc) continue;  // self
                int g = gbase + (int)ix;
                float4 A = pp4[(g >> 1) * 2 + 0];
                float4 B = pp4[(g >> 1) * 2 + 1];
                bool ch = (ix & 1);
                uint32_t db = d2exact(mx, my, mz, sqi,
                                      ch ? A.y : A.x, ch ? A.w : A.z,
                                      ch ? B.y : B.x, ch ? B.w : B.z);
                uint64_t k64 = ((uint64_t)db << 32) | ix;
                if (k64 < S[0]) {
                    bool sh[KK];
                    sh[0] = true;
#pragma unroll
                    for (int t = 1; t < KK; t++) sh[t] = (k64 < S[t]);
#pragma unroll
                    for (int t = 0; t < KK; t++) {
                        uint64_t vac = sh[t] ? k64 : S[t];
                        S[t] = (t + 1 < KK) ? (sh[t + 1] ? S[t + 1] : vac) : vac;
                    }
                }
            }
        }
#pragma unroll
        for (int t = 0; t < KK; t++) {
            int jl = (int)(S[t] & 0xffffffffu);
            int gj = gbase + jl;
            int p = atomicAdd(&cnt[gj], 1);
            if (colfix) {
                if (p < 64) colfix[(gj << 6) | p] = gq;
            } else {
                nbr[gq * KK + t] = gj;
            }
        }
    }
#undef D8P
}

// ---------------------------------------------------------------------------
// Bucket-path output: 2 nodes per wave, 32 lanes/node = 16 feature-quads x
// 2 edge-halves (even/odd int4 quads). Halves merged via shfl_xor(16) on the
// 4-dim partial sums; after the merge, EACH half's 16 lanes hold the complete
// per-quad sums, so the 1/2/4/8 shfl reduction within a half yields the full
// L1 norm. Batch = blockIdx&15 -> XCD L2 affinity.
// ---------------------------------------------------------------------------
__global__ __launch_bounds__(256) void out_bucket_kernel(const float4* __restrict__ x4,
                                                         const int* __restrict__ colfix,
                                                         const int* __restrict__ cnt,
                                                         float* __restrict__ out) {
    const int b = blockIdx.x;             // grid = TOTAL*32/256 = 8192
    const int g = b & 15;                 // batch
    const int i = b >> 4;                 // block-within-batch, 0..511 (8 nodes)
    const int l = threadIdx.x & 31;
    const int n = (g << 12) | (i << 3) | (threadIdx.x >> 5);
    const int s = l & 15;                 // feature quad
    const int half = l >> 4;              // edge half (even/odd int4 quads)
    const int c = cnt[n];
    const int cc = (c > 64) ? 64 : c;
    const int4* cf4 = (const int4*)(colfix + ((size_t)n << 6));
    float4 acc = make_float4(0.f, 0.f, 0.f, 0.f);
    for (int eb = half * 4; eb < cc; eb += 8) {
        int4 Q = cf4[eb >> 2];
        float4 v0 = x4[((size_t)Q.x << 4) | s];
        acc.x += v0.x; acc.y += v0.y; acc.z += v0.z; acc.w += v0.w;
        if (eb + 1 < cc) {
            float4 v1 = x4[((size_t)Q.y << 4) | s];
            acc.x += v1.x; acc.y += v1.y; acc.z += v1.z; acc.w += v1.w;
        }
        if (eb + 2 < cc) {
            float4 v2 = x4[((size_t)Q.z << 4) | s];
            acc.x += v2.x; acc.y += v2.y; acc.z += v2.z; acc.w += v2.w;
        }
        if (eb + 3 < cc) {
            float4 v3 = x4[((size_t)Q.w << 4) | s];
            acc.x += v3.x; acc.y += v3.y; acc.z += v3.z; acc.w += v3.w;
        }
    }
    // merge edge-halves (lanes l and l^16 hold partial sums of same 4 dims)
    acc.x += __shfl_xor(acc.x, 16, 64);
    acc.y += __shfl_xor(acc.y, 16, 64);
    acc.z += __shfl_xor(acc.z, 16, 64);
    acc.w += __shfl_xor(acc.w, 16, 64);
    const float inv = 1.0f / (float)(c > 1 ? c : 1);
    float4 mn = x4[((size_t)n << 4) | s];
    float v = fabsf(mn.x - acc.x * inv) + fabsf(mn.y - acc.y * inv) +
              fabsf(mn.z - acc.z * inv) + fabsf(mn.w - acc.w * inv);
    v += __shfl_xor(v, 1, 64);
    v += __shfl_xor(v, 2, 64);
    v += __shfl_xor(v, 4, 64);
    v += __shfl_xor(v, 8, 64);
    if (l == 0) out[n] = v;
}

// ------------------------- fallback path (small ws) -------------------------
__global__ __launch_bounds__(1024) void scan_kernel(const int* __restrict__ cnt,
                                                    int* __restrict__ offs) {
    __shared__ int lds[1024];
    const int t = threadIdx.x;
    const int base = t * 64;
    int s = 0;
    for (int i = 0; i < 64; i++) s += cnt[base + i];
    lds[t] = s;
    __syncthreads();
    for (int off = 1; off < 1024; off <<= 1) {
        int v = (t >= off) ? lds[t - off] : 0;
        __syncthreads();
        lds[t] += v;
        __syncthreads();
    }
    int run = lds[t] - s;
    for (int i = 0; i < 64; i++) {
        offs[base + i] = run;
        run += cnt[base + i];
    }
}

__global__ __launch_bounds__(256) void fill_kernel(const int* __restrict__ nbr,
                                                   int* __restrict__ offs,
                                                   int* __restrict__ col) {
    const int i = blockIdx.x * 256 + threadIdx.x;
#pragma unroll
    for (int t = 0; t < KK; t++) {
        int j = nbr[i * KK + t];
        int p = atomicAdd(&offs[j], 1);
        col[p] = i;
    }
}

__global__ __launch_bounds__(256) void out_kernel(const float* __restrict__ x,
                                                  const int* __restrict__ col,
                                                  const int* __restrict__ offs_end,
                                                  const int* __restrict__ cnt,
                                                  float* __restrict__ out) {
    const int gtid = blockIdx.x * 256 + threadIdx.x;
    const int n = gtid >> 6;
    const int lane = gtid & 63;
    const int c = cnt[n];
    const int end = offs_end[n];
    const int start = end - c;
    float s = 0.0f;
    for (int e = start; e < end; e++) {
        int i = col[e];
        s += x[(size_t)i * FD + lane];
    }
    float mean = s / (float)(c > 1 ? c : 1);
    float v = fabsf(x[(size_t)n * FD + lane] - mean);
#pragma unroll
    for (int off = 32; off; off >>= 1) v += __shfl_xor(v, off, 64);
    if (lane == 0) out[n] = v;
}

extern "C" void kernel_launch(void* const* d_in, const int* in_sizes, int n_in,
                              void* d_out, int out_size, void* d_ws, size_t ws_size,
                              hipStream_t stream) {
    const float* x = (const float*)d_in[0];
    const float* pos = (const float*)d_in[1];
    float* out = (float*)d_out;

    char* ws = (char*)d_ws;
    float4* pp4 = (float4*)(ws + 0);            // 1,048,576 B
    int* cnt = (int*)(ws + 1048576);            //   262,144 B
    // bucket path (needs 18.1 MB):
    int* colfix = (int*)(ws + 1310720);         // TOTAL*64*4 = 16,777,216 B
    // fallback path (needs 6.8 MB):
    int* nbr = (int*)(ws + 1310720);            // 2,621,440 B
    int* offs = (int*)(ws + 3932160);           //   262,144 B
    int* col = (int*)(ws + 4194304);            // 2,621,440 B

    const bool bucket = ws_size >= (size_t)(1310720 + TOTAL * 64 * 4);

    hipLaunchKernelGGL(prep_kernel, dim3(TOTAL / 2 / 256), dim3(256), 0, stream, pos, pp4, cnt);
    hipLaunchKernelGGL(knn_kernel, dim3(TOTAL / QG), dim3(512), 0, stream, pp4, cnt,
                       bucket ? colfix : (int*)nullptr, bucket ? (int*)nullptr : nbr);
    if (bucket) {
        hipLaunchKernelGGL(out_bucket_kernel, dim3(TOTAL * 32 / 256), dim3(256), 0, stream,
                           (const float4*)x, colfix, cnt, out);
    } else {
        hipLaunchKernelGGL(scan_kernel, dim3(1), dim3(1024), 0, stream, cnt, offs);
        hipLaunchKernelGGL(fill_kernel, dim3(TOTAL / 256), dim3(256), 0, stream, nbr, offs, col);
        hipLaunchKernelGGL(out_kernel, dim3(TOTAL * FD / 256), dim3(256), 0, stream,
                           x, col, offs, cnt, out);
    }
}

// Round 12
// 185.479 us; speedup vs baseline: 1.1169x; 1.1169x over previous
//
#include <hip/hip_runtime.h>
#include <stdint.h>

#define NB 16
#define NN 4096
#define KK 10
#define NL 11       // pass1 list size: 11th-smallest oct-min -> tau
#define FD 64
#define TOTAL (NB * NN)
#define NW 8        // waves per knn block
#define CH 512      // candidates per wave chunk (NW*CH == NN)
#define SOCT 32     // sampled octs per chunk (first 256 cands) for pass1
#define QG 64       // queries per block (one per lane)
#define WCAP 24     // survivor cap per (query,wave) cell (mean ~2.8, huge margin)
#define WPITCH 25   // cell pitch in halfwords

#define INFF __int_as_float(0x7f800000)

typedef float f2 __attribute__((ext_vector_type(2)));

// Packed membership distance: candidate coords are wave-uniform f2 (SGPR
// pairs); vx2/vy2/vz2/sqi are per-lane splats. Lowers to v_pk_fma_f32 with
// one SGPR-pair operand. MEMBERSHIP ONLY - final keys use d2exact.
__device__ __forceinline__ f2 FdP(f2 cx, f2 cy, f2 cz, f2 cq,
                                  f2 vx2, f2 vy2, f2 vz2, f2 sqi2) {
#pragma clang fp contract(fast)
    f2 t = sqi2 + cq;
    t = vx2 * cx + t;
    t = vy2 * cy + t;
    t = vz2 * cz + t;
    return t;
}

// EXACT numpy rounding - frozen since round 1 (absmax 0.75). DO NOT CHANGE.
__device__ __forceinline__ uint32_t d2exact(float mx, float my, float mz, float sqi,
                                            float cx, float cy, float cz, float cw) {
    float dot = __fadd_rn(__fadd_rn(__fmul_rn(mx, cx), __fmul_rn(my, cy)),
                          __fmul_rn(mz, cz));
    float d2 = __fsub_rn(__fadd_rn(sqi, cw), __fmul_rn(2.0f, dot));
    return __float_as_uint(d2);
}

// ---------------------------------------------------------------------------
// Prep: pair-packed positions + zero cnt.
// pp4[2p]={x0,x1,y0,y1}, pp4[2p+1]={z0,z1,q0,q1}, q=(x*x+y*y)+z*z numpy-exact.
// ---------------------------------------------------------------------------
__global__ __launch_bounds__(256) void prep_kernel(const float* __restrict__ pos,
                                                   float4* __restrict__ pp4,
                                                   int* __restrict__ cnt) {
    const int p = blockIdx.x * 256 + threadIdx.x;  // pair index, < TOTAL/2
    const float* s = pos + (size_t)p * 6;
    float x0 = s[0], y0 = s[1], z0 = s[2];
    float x1 = s[3], y1 = s[4], z1 = s[5];
    float q0 = __fadd_rn(__fadd_rn(__fmul_rn(x0, x0), __fmul_rn(y0, y0)),
                         __fmul_rn(z0, z0));
    float q1 = __fadd_rn(__fadd_rn(__fmul_rn(x1, x1), __fmul_rn(y1, y1)),
                         __fmul_rn(z1, z1));
    pp4[2 * p + 0] = make_float4(x0, x1, y0, y1);
    pp4[2 * p + 1] = make_float4(z0, z1, q0, q1);
    cnt[2 * p + 0] = 0;
    cnt[2 * p + 1] = 0;
}

// ---------------------------------------------------------------------------
// kNN: block = 512 thr = 8 waves; lane = query, wave = 512-cand chunk.
// Candidate data wave-uniform (scalar loads as f2); distance = v_pk_fma (2
// slots/cand). Pass1: top-11 oct-mins over first 256 cands. Merge: tau =
// 11th-smallest octmin of 8-wave union (+guard). Pass2: packed full-chunk
// replay with PAIR-granularity push guards. Survivors to private
// (query,wave) u16 LDS cells. Select: exact-rescore survivors, (d2,idx)
// top-10, skip self, write edges.
// Batch = blockIdx&15 -> XCD L2 affinity for the 1MB/batch pp4 slice.
// R12 note: this is the measured optimum of the tau-tradeoff family
// (R7 oct-guards 117us; R8 ctz-walk 140us; R11 loose-tau 131us; this 114us).
// ---------------------------------------------------------------------------
__global__ __launch_bounds__(512, 8) void knn_kernel(const float4* __restrict__ pp4,
                                                     int* __restrict__ cnt,
                                                     int* __restrict__ colfix,
                                                     int* __restrict__ nbr) {
    __shared__ uint32_t smem[6400];      // pass1 lists (5632 w) then u16 pools (6400 w)
    __shared__ float tau_s[QG];
    __shared__ uint32_t qcntw[QG * NW];
    float* listf = (float*)smem;
    uint16_t* pool16 = (uint16_t*)smem;

    const int tid = threadIdx.x;
    const int lane = tid & 63;
    const int w = __builtin_amdgcn_readfirstlane(tid >> 6);
    const int batch = blockIdx.x & 15;                  // XCD-affinity swizzle
    const int qloc = ((blockIdx.x >> 4) << 6) | lane;   // batch-local query idx
    const int gbase = batch << 12;
    const int gq = gbase + qloc;

    // my query position (from pair-packed array)
    float4 mA = pp4[(gq >> 1) * 2 + 0];
    float4 mB = pp4[(gq >> 1) * 2 + 1];
    const bool hi = (qloc & 1);
    const float mx = hi ? mA.y : mA.x;
    const float my = hi ? mA.w : mA.z;
    const float mz = hi ? mB.y : mB.x;
    const float sqi = hi ? mB.w : mB.z;
    const f2 vx22 = {__fmul_rn(-2.0f, mx), __fmul_rn(-2.0f, mx)};
    const f2 vy22 = {__fmul_rn(-2.0f, my), __fmul_rn(-2.0f, my)};
    const f2 vz22 = {__fmul_rn(-2.0f, mz), __fmul_rn(-2.0f, mz)};
    const f2 sqi22 = {sqi, sqi};

    // chunk base as f2: pair p -> f2s {x01,y01,z01,q01} at 4p..4p+3
    const f2* __restrict__ cp2 = (const f2*)(pp4 + (size_t)(gbase + w * CH));

#define D8P(cb2)                                                      \
    f2 X0 = (cb2)[0],  Y0 = (cb2)[1],  Z0 = (cb2)[2],  Q0 = (cb2)[3]; \
    f2 X1 = (cb2)[4],  Y1 = (cb2)[5],  Z1 = (cb2)[6],  Q1 = (cb2)[7]; \
    f2 X2 = (cb2)[8],  Y2 = (cb2)[9],  Z2 = (cb2)[10], Q2 = (cb2)[11];\
    f2 X3 = (cb2)[12], Y3 = (cb2)[13], Z3 = (cb2)[14], Q3 = (cb2)[15];\
    f2 e0 = FdP(X0, Y0, Z0, Q0, vx22, vy22, vz22, sqi22);             \
    f2 e1 = FdP(X1, Y1, Z1, Q1, vx22, vy22, vz22, sqi22);             \
    f2 e2 = FdP(X2, Y2, Z2, Q2, vx22, vy22, vz22, sqi22);             \
    f2 e3 = FdP(X3, Y3, Z3, Q3, vx22, vy22, vz22, sqi22);

    // ---- pass 1: top-11 oct-mins over sampled first 256 cands of chunk
    float L[NL];
#pragma unroll
    for (int t = 0; t < NL; t++) L[t] = INFF;

#pragma unroll 2
    for (int o = 0; o < SOCT; ++o) {
        const f2* cb2 = cp2 + o * 16;
        D8P(cb2);
        float m = fminf(fminf(fminf(e0.x, e0.y), fminf(e1.x, e1.y)),
                        fminf(fminf(e2.x, e2.y), fminf(e3.x, e3.y)));
#pragma unroll
        for (int t = 0; t < NL - 1; ++t) L[t] = __builtin_amdgcn_fmed3f(L[t], L[t + 1], m);
        L[NL - 1] = fminf(L[NL - 1], m);
    }
#pragma unroll
    for (int t = 0; t < NL; t++) listf[tid * NL + t] = L[t];
    __syncthreads();

    // ---- merge: 11th-smallest oct-min of the 8-list union -> tau
    if (tid < QG) {
        int p[NW];
#pragma unroll
        for (int u = 0; u < NW; u++) p[u] = NL - 1;  // descending lists; tail = min
        float tau = INFF;
        for (int it = 0; it < NL; ++it) {
            float best = INFF;
            int bw = 0;
#pragma unroll
            for (int u = 0; u < NW; u++) {
                float v = (p[u] >= 0) ? listf[((u << 6) | tid) * NL + p[u]] : INFF;
                if (v < best) { best = v; bw = u; }
            }
            p[bw]--;
            tau = best;
        }
        tau_s[tid] = tau;
    }
    __syncthreads();  // merge reads done; pool16 may now overwrite list region

    // ---- pass 2: packed full-chunk replay into private (query,wave) u16 cell
    // guard: covers |packed - exact| rigorously (order-stat bound + eps)
    const float tau = tau_s[lane] * 1.0001f + 1e-5f;
    const uint32_t cell0 = (uint32_t)((lane * NW + w) * WPITCH);  // halfword idx
    uint32_t cpos = cell0;
#pragma unroll 2
    for (int o = 0; o < CH / 8; ++o) {
        const f2* cb2 = cp2 + o * 16;
        D8P(cb2);
        const uint32_t jb = (uint32_t)(w * CH + o * 8);
        bool h0 = e0.x <= tau, h1 = e0.y <= tau, h2 = e1.x <= tau, h3 = e1.y <= tau;
        bool h4 = e2.x <= tau, h5 = e2.y <= tau, h6 = e3.x <= tau, h7 = e3.y <= tau;
#define PUSH(hv, off)                                              \
        if ((hv) && cpos < cell0 + WCAP) {                         \
            pool16[cpos] = (uint16_t)(jb + (off));                 \
            cpos++;                                                \
        }
        if (h0 | h1) { PUSH(h0, 0) PUSH(h1, 1) }
        if (h2 | h3) { PUSH(h2, 2) PUSH(h3, 3) }
        if (h4 | h5) { PUSH(h4, 4) PUSH(h5, 5) }
        if (h6 | h7) { PUSH(h6, 6) PUSH(h7, 7) }
#undef PUSH
    }
    qcntw[lane * NW + w] = cpos - cell0;
    __syncthreads();

    // ---- select: exact rescore of survivors, (d2,idx) top-10, skip self
    if (tid < QG) {
        uint64_t S[KK];
#pragma unroll
        for (int t = 0; t < KK; t++) S[t] = ~0ull;
#pragma unroll
        for (int u = 0; u < NW; u++) {
            uint32_t c2 = qcntw[tid * NW + u];
            const uint16_t* st = pool16 + (tid * NW + u) * WPITCH;
            for (uint32_t e = 0; e < c2; ++e) {
                uint32_t ix = st[e];
                if (ix == (uint32_t)qloc) continue;  // self
                int g = gbase + (int)ix;
                float4 A = pp4[(g >> 1) * 2 + 0];
                float4 B = pp4[(g >> 1) * 2 + 1];
                bool ch = (ix & 1);
                uint32_t db = d2exact(mx, my, mz, sqi,
                                      ch ? A.y : A.x, ch ? A.w : A.z,
                                      ch ? B.y : B.x, ch ? B.w : B.z);
                uint64_t k64 = ((uint64_t)db << 32) | ix;
                if (k64 < S[0]) {
                    bool sh[KK];
                    sh[0] = true;
#pragma unroll
                    for (int t = 1; t < KK; t++) sh[t] = (k64 < S[t]);
#pragma unroll
                    for (int t = 0; t < KK; t++) {
                        uint64_t vac = sh[t] ? k64 : S[t];
                        S[t] = (t + 1 < KK) ? (sh[t + 1] ? S[t + 1] : vac) : vac;
                    }
                }
            }
        }
#pragma unroll
        for (int t = 0; t < KK; t++) {
            int jl = (int)(S[t] & 0xffffffffu);
            int gj = gbase + jl;
            int p = atomicAdd(&cnt[gj], 1);
            if (colfix) {
                if (p < 64) colfix[(gj << 6) | p] = gq;
            } else {
                nbr[gq * KK + t] = gj;
            }
        }
    }
#undef D8P
}

// ---------------------------------------------------------------------------
// Bucket-path output: 2 nodes per wave, 32 lanes/node = 16 feature-quads x
// 2 edge-halves (even/odd int4 quads). Halves merged via shfl_xor(16) on the
// 4-dim partial sums; after the merge, EACH half's 16 lanes hold the complete
// per-quad sums, so the 1/2/4/8 shfl reduction within a half yields the full
// L1 norm. Batch = blockIdx&15 -> XCD L2 affinity.
// ---------------------------------------------------------------------------
__global__ __launch_bounds__(256) void out_bucket_kernel(const float4* __restrict__ x4,
                                                         const int* __restrict__ colfix,
                                                         const int* __restrict__ cnt,
                                                         float* __restrict__ out) {
    const int b = blockIdx.x;             // grid = TOTAL*32/256 = 8192
    const int g = b & 15;                 // batch
    const int i = b >> 4;                 // block-within-batch, 0..511 (8 nodes)
    const int l = threadIdx.x & 31;
    const int n = (g << 12) | (i << 3) | (threadIdx.x >> 5);
    const int s = l & 15;                 // feature quad
    const int half = l >> 4;              // edge half (even/odd int4 quads)
    const int c = cnt[n];
    const int cc = (c > 64) ? 64 : c;
    const int4* cf4 = (const int4*)(colfix + ((size_t)n << 6));
    float4 acc = make_float4(0.f, 0.f, 0.f, 0.f);
    for (int eb = half * 4; eb < cc; eb += 8) {
        int4 Q = cf4[eb >> 2];
        float4 v0 = x4[((size_t)Q.x << 4) | s];
        acc.x += v0.x; acc.y += v0.y; acc.z += v0.z; acc.w += v0.w;
        if (eb + 1 < cc) {
            float4 v1 = x4[((size_t)Q.y << 4) | s];
            acc.x += v1.x; acc.y += v1.y; acc.z += v1.z; acc.w += v1.w;
        }
        if (eb + 2 < cc) {
            float4 v2 = x4[((size_t)Q.z << 4) | s];
            acc.x += v2.x; acc.y += v2.y; acc.z += v2.z; acc.w += v2.w;
        }
        if (eb + 3 < cc) {
            float4 v3 = x4[((size_t)Q.w << 4) | s];
            acc.x += v3.x; acc.y += v3.y; acc.z += v3.z; acc.w += v3.w;
        }
    }
    // merge edge-halves (lanes l and l^16 hold partial sums of same 4 dims)
    acc.x += __shfl_xor(acc.x, 16, 64);
    acc.y += __shfl_xor(acc.y, 16, 64);
    acc.z += __shfl_xor(acc.z, 16, 64);
    acc.w += __shfl_xor(acc.w, 16, 64);
    const float inv = 1.0f / (float)(c > 1 ? c : 1);
    float4 mn = x4[((size_t)n << 4) | s];
    float v = fabsf(mn.x - acc.x * inv) + fabsf(mn.y - acc.y * inv) +
              fabsf(mn.z - acc.z * inv) + fabsf(mn.w - acc.w * inv);
    v += __shfl_xor(v, 1, 64);
    v += __shfl_xor(v, 2, 64);
    v += __shfl_xor(v, 4, 64);
    v += __shfl_xor(v, 8, 64);
    if (l == 0) out[n] = v;
}

// ------------------------- fallback path (small ws) -------------------------
__global__ __launch_bounds__(1024) void scan_kernel(const int* __restrict__ cnt,
                                                    int* __restrict__ offs) {
    __shared__ int lds[1024];
    const int t = threadIdx.x;
    const int base = t * 64;
    int s = 0;
    for (int i = 0; i < 64; i++) s += cnt[base + i];
    lds[t] = s;
    __syncthreads();
    for (int off = 1; off < 1024; off <<= 1) {
        int v = (t >= off) ? lds[t - off] : 0;
        __syncthreads();
        lds[t] += v;
        __syncthreads();
    }
    int run = lds[t] - s;
    for (int i = 0; i < 64; i++) {
        offs[base + i] = run;
        run += cnt[base + i];
    }
}

__global__ __launch_bounds__(256) void fill_kernel(const int* __restrict__ nbr,
                                                   int* __restrict__ offs,
                                                   int* __restrict__ col) {
    const int i = blockIdx.x * 256 + threadIdx.x;
#pragma unroll
    for (int t = 0; t < KK; t++) {
        int j = nbr[i * KK + t];
        int p = atomicAdd(&offs[j], 1);
        col[p] = i;
    }
}

__global__ __launch_bounds__(256) void out_kernel(const float* __restrict__ x,
                                                  const int* __restrict__ col,
                                                  const int* __restrict__ offs_end,
                                                  const int* __restrict__ cnt,
                                                  float* __restrict__ out) {
    const int gtid = blockIdx.x * 256 + threadIdx.x;
    const int n = gtid >> 6;
    const int lane = gtid & 63;
    const int c = cnt[n];
    const int end = offs_end[n];
    const int start = end - c;
    float s = 0.0f;
    for (int e = start; e < end; e++) {
        int i = col[e];
        s += x[(size_t)i * FD + lane];
    }
    float mean = s / (float)(c > 1 ? c : 1);
    float v = fabsf(x[(size_t)n * FD + lane] - mean);
#pragma unroll
    for (int off = 32; off; off >>= 1) v += __shfl_xor(v, off, 64);
    if (lane == 0) out[n] = v;
}

extern "C" void kernel_launch(void* const* d_in, const int* in_sizes, int n_in,
                              void* d_out, int out_size, void* d_ws, size_t ws_size,
                              hipStream_t stream) {
    const float* x = (const float*)d_in[0];
    const float* pos = (const float*)d_in[1];
    float* out = (float*)d_out;

    char* ws = (char*)d_ws;
    float4* pp4 = (float4*)(ws + 0);            // 1,048,576 B
    int* cnt = (int*)(ws + 1048576);            //   262,144 B
    // bucket path (needs 18.1 MB):
    int* colfix = (int*)(ws + 1310720);         // TOTAL*64*4 = 16,777,216 B
    // fallback path (needs 6.8 MB):
    int* nbr = (int*)(ws + 1310720);            // 2,621,440 B
    int* offs = (int*)(ws + 3932160);           //   262,144 B
    int* col = (int*)(ws + 4194304);            // 2,621,440 B

    const bool bucket = ws_size >= (size_t)(1310720 + TOTAL * 64 * 4);

    hipLaunchKernelGGL(prep_kernel, dim3(TOTAL / 2 / 256), dim3(256), 0, stream, pos, pp4, cnt);
    hipLaunchKernelGGL(knn_kernel, dim3(TOTAL / QG), dim3(512), 0, stream, pp4, cnt,
                       bucket ? colfix : (int*)nullptr, bucket ? (int*)nullptr : nbr);
    if (bucket) {
        hipLaunchKernelGGL(out_bucket_kernel, dim3(TOTAL * 32 / 256), dim3(256), 0, stream,
                           (const float4*)x, colfix, cnt, out);
    } else {
        hipLaunchKernelGGL(scan_kernel, dim3(1), dim3(1024), 0, stream, cnt, offs);
        hipLaunchKernelGGL(fill_kernel, dim3(TOTAL / 256), dim3(256), 0, stream, nbr, offs, col);
        hipLaunchKernelGGL(out_kernel, dim3(TOTAL * FD / 256), dim3(256), 0, stream,
                           x, col, offs, cnt, out);
    }
}